// Round 5
// baseline (10124.328 us; speedup 1.0000x reference)
//
#include <hip/hip_runtime.h>
#include <cstdint>

// ---------------------------------------------------------------------------
// ConvGRU-Attention autoencoder, fp32. B=64, T=128, F=64 (1-D k=3 conv over F).
//   * conv split: x-part precomputed (parallel), h-part sequential per batch.
//   * t chunked x4 (TC=32) to bound workspace.
//   * attention: qlen==1 -> fold W_k into query, W_v past softmax (exact).
//   * R5: gru_rec: threads = HC*16 (1 oc-row/thread), shfl halos (no scalar
//     LDS reads), unpadded [HC][64] LDS, 2-barrier scheme kept. Packs fused.
// ---------------------------------------------------------------------------

#define B_  64
#define T_  128
#define TC  32
#define NCH 4

__device__ __forceinline__ float wsum(float v) {
#pragma unroll
  for (int m = 32; m > 0; m >>= 1) v += __shfl_xor(v, m, 64);
  return v;
}
__device__ __forceinline__ float wmaxr(float v) {
#pragma unroll
  for (int m = 32; m > 0; m >>= 1) v = fmaxf(v, __shfl_xor(v, m, 64));
  return v;
}
__device__ __forceinline__ float sigmoidf_(float x) {
  return 1.f / (1.f + __expf(-x));
}
__device__ __forceinline__ float tanhf_(float x) {
  x = fminf(fmaxf(x, -15.f), 15.f);
  float e2 = __expf(2.f * x);
  return (e2 - 1.f) / (e2 + 1.f);
}

// --------------------------------------------------------------------------
// Fused weight repack: 16 jobs in one launch. grid = (192, 16).
// job j: dst[i] = src[((oc*INTOT + ic0 + ic)*3 + dk)*3 + 1], i over OC*icN*3.
// --------------------------------------------------------------------------
struct PackArgs {
  const float* src[16];
  float* dst[16];
  int intot[16];
  int ic0[16];
  int icn[16];
  int oc[16];
};

__global__ __launch_bounds__(256) void pack_all_kernel(PackArgs pa) {
  const int j = blockIdx.y;
  const int icN = pa.icn[j];
  const int total = pa.oc[j] * icN * 3;
  const int i = blockIdx.x * 256 + threadIdx.x;
  if (i >= total) return;
  const int per_oc = icN * 3;
  const int oc = i / per_oc;
  const int rem = i - oc * per_oc;
  const int ic = rem / 3, dk = rem - ic * 3;
  pa.dst[j][i] =
      pa.src[j][((size_t)(oc * pa.intot[j] + pa.ic0[j] + ic) * 3 + dk) * 3 + 1];
}

// --------------------------------------------------------------------------
// x-part of both convs (gates then cand) for one t-chunk. One WG per (b,tl).
// --------------------------------------------------------------------------
template <int INC, int OG, int OCC>
__global__ __launch_bounds__(256) void conv_x_kernel(
    const float* __restrict__ seq, int seqC, size_t sB,
    const float* __restrict__ ctx,
    const float* __restrict__ Wgx, const float* __restrict__ Wcx,
    const float* __restrict__ bg, const float* __restrict__ bc,
    float* __restrict__ out) {
  constexpr int OCT = OG + OCC;
  constexpr int NJ = OG / 32;
  constexpr int NJC = OCC / 32;
  const int btl = blockIdx.x;
  const int b = btl >> 5;
  const int tl = btl & 31;
  const int ocg = threadIdx.x >> 3;
  const int f0 = (threadIdx.x & 7) << 3;
  __shared__ float sin_[INC][72];  // halo at [0], data 1..64

  for (int idx = threadIdx.x; idx < INC * 72; idx += 256) {
    int ic = idx / 72, ff = idx - ic * 72;
    float v = 0.f;
    if (ff >= 1 && ff <= 64) {
      int fs = ff - 1;
      v = (ic < seqC)
              ? seq[(size_t)b * sB + (size_t)tl * seqC * 64 + ic * 64 + fs]
              : ctx[((size_t)b * (INC - seqC) + (ic - seqC)) * 64 + fs];
    }
    sin_[ic][ff] = v;
  }
  __syncthreads();

  if constexpr (INC >= 4) {
    // ---- gates ----
    {
      float acc[NJ][8];
#pragma unroll
      for (int j = 0; j < NJ; ++j) {
        float bb = bg[ocg + 32 * j];
#pragma unroll
        for (int ff = 0; ff < 8; ++ff) acc[j][ff] = bb;
      }
      for (int ic0 = 0; ic0 < INC; ic0 += 4) {
        float hv[4][10];
#pragma unroll
        for (int q = 0; q < 4; ++q) {
          float4 a4 = *(const float4*)&sin_[ic0 + q][f0];
          float4 b4 = *(const float4*)&sin_[ic0 + q][f0 + 4];
          float2 c2 = *(const float2*)&sin_[ic0 + q][f0 + 8];
          hv[q][0] = a4.x; hv[q][1] = a4.y; hv[q][2] = a4.z; hv[q][3] = a4.w;
          hv[q][4] = b4.x; hv[q][5] = b4.y; hv[q][6] = b4.z; hv[q][7] = b4.w;
          hv[q][8] = c2.x; hv[q][9] = c2.y;
        }
#pragma unroll
        for (int j = 0; j < NJ; ++j) {
          const int oc = ocg + 32 * j;
          const float4* w4 = (const float4*)(Wgx + ((size_t)oc * INC + ic0) * 3);
          float4 wa = w4[0], wb = w4[1], wc4 = w4[2];
          const float wt[12] = {wa.x, wa.y, wa.z, wa.w, wb.x, wb.y, wb.z, wb.w,
                                wc4.x, wc4.y, wc4.z, wc4.w};
#pragma unroll
          for (int q = 0; q < 4; ++q) {
            const float w0 = wt[3 * q], w1 = wt[3 * q + 1], w2 = wt[3 * q + 2];
#pragma unroll
            for (int ff = 0; ff < 8; ++ff)
              acc[j][ff] = fmaf(w0, hv[q][ff], fmaf(w1, hv[q][ff + 1], fmaf(w2, hv[q][ff + 2], acc[j][ff])));
          }
        }
      }
#pragma unroll
      for (int j = 0; j < NJ; ++j) {
        float* dst = out + ((size_t)btl * OCT + ocg + 32 * j) * 64 + f0;
        *(float4*)dst = make_float4(acc[j][0], acc[j][1], acc[j][2], acc[j][3]);
        *(float4*)(dst + 4) = make_float4(acc[j][4], acc[j][5], acc[j][6], acc[j][7]);
      }
    }
    // ---- cand ----
    {
      float acc[NJC][8];
#pragma unroll
      for (int j = 0; j < NJC; ++j) {
        float bb = bc[ocg + 32 * j];
#pragma unroll
        for (int ff = 0; ff < 8; ++ff) acc[j][ff] = bb;
      }
      for (int ic0 = 0; ic0 < INC; ic0 += 4) {
        float hv[4][10];
#pragma unroll
        for (int q = 0; q < 4; ++q) {
          float4 a4 = *(const float4*)&sin_[ic0 + q][f0];
          float4 b4 = *(const float4*)&sin_[ic0 + q][f0 + 4];
          float2 c2 = *(const float2*)&sin_[ic0 + q][f0 + 8];
          hv[q][0] = a4.x; hv[q][1] = a4.y; hv[q][2] = a4.z; hv[q][3] = a4.w;
          hv[q][4] = b4.x; hv[q][5] = b4.y; hv[q][6] = b4.z; hv[q][7] = b4.w;
          hv[q][8] = c2.x; hv[q][9] = c2.y;
        }
#pragma unroll
        for (int j = 0; j < NJC; ++j) {
          const int oc = ocg + 32 * j;
          const float4* w4 = (const float4*)(Wcx + ((size_t)oc * INC + ic0) * 3);
          float4 wa = w4[0], wb = w4[1], wc4 = w4[2];
          const float wt[12] = {wa.x, wa.y, wa.z, wa.w, wb.x, wb.y, wb.z, wb.w,
                                wc4.x, wc4.y, wc4.z, wc4.w};
#pragma unroll
          for (int q = 0; q < 4; ++q) {
            const float w0 = wt[3 * q], w1 = wt[3 * q + 1], w2 = wt[3 * q + 2];
#pragma unroll
            for (int ff = 0; ff < 8; ++ff)
              acc[j][ff] = fmaf(w0, hv[q][ff], fmaf(w1, hv[q][ff + 1], fmaf(w2, hv[q][ff + 2], acc[j][ff])));
          }
        }
      }
#pragma unroll
      for (int j = 0; j < NJC; ++j) {
        float* dst = out + ((size_t)btl * OCT + OG + ocg + 32 * j) * 64 + f0;
        *(float4*)dst = make_float4(acc[j][0], acc[j][1], acc[j][2], acc[j][3]);
        *(float4*)(dst + 4) = make_float4(acc[j][4], acc[j][5], acc[j][6], acc[j][7]);
      }
    }
  } else {
    // INC == 1 (encoder layer 0 x-part).
    float hv[10];
    {
      float4 a4 = *(const float4*)&sin_[0][f0];
      float4 b4 = *(const float4*)&sin_[0][f0 + 4];
      float2 c2 = *(const float2*)&sin_[0][f0 + 8];
      hv[0] = a4.x; hv[1] = a4.y; hv[2] = a4.z; hv[3] = a4.w;
      hv[4] = b4.x; hv[5] = b4.y; hv[6] = b4.z; hv[7] = b4.w;
      hv[8] = c2.x; hv[9] = c2.y;
    }
#pragma unroll
    for (int j = 0; j < NJ; ++j) {
      const int oc = ocg + 32 * j;
      const float w0 = Wgx[oc * 3], w1 = Wgx[oc * 3 + 1], w2 = Wgx[oc * 3 + 2];
      float acc[8];
#pragma unroll
      for (int ff = 0; ff < 8; ++ff)
        acc[ff] = fmaf(w0, hv[ff], fmaf(w1, hv[ff + 1], fmaf(w2, hv[ff + 2], bg[oc])));
      float* dst = out + ((size_t)btl * OCT + oc) * 64 + f0;
      *(float4*)dst = make_float4(acc[0], acc[1], acc[2], acc[3]);
      *(float4*)(dst + 4) = make_float4(acc[4], acc[5], acc[6], acc[7]);
    }
#pragma unroll
    for (int j = 0; j < NJC; ++j) {
      const int oc = ocg + 32 * j;
      const float w0 = Wcx[oc * 3], w1 = Wcx[oc * 3 + 1], w2 = Wcx[oc * 3 + 2];
      float acc[8];
#pragma unroll
      for (int ff = 0; ff < 8; ++ff)
        acc[ff] = fmaf(w0, hv[ff], fmaf(w1, hv[ff + 1], fmaf(w2, hv[ff + 2], bc[oc])));
      float* dst = out + ((size_t)btl * OCT + OG + oc) * 64 + f0;
      *(float4*)dst = make_float4(acc[0], acc[1], acc[2], acc[3]);
      *(float4*)(dst + 4) = make_float4(acc[4], acc[5], acc[6], acc[7]);
    }
  }
}

// --------------------------------------------------------------------------
// GRU recurrence v5. One WG of HC*16 threads per batch; thread (ocg=tid>>4,
// f0=(tid&15)*4) owns exactly one channel row's f-window: h[ocg][f0..f0+3].
// LDS: Hs (h) / Rs (r*h), both [HC][64] unpadded; halos via __shfl from the
// b128's edge words (no scalar LDS reads). 2 barriers/step:
//   phase A: read Hs -> r,u; write Rs[own]; barrier
//   phase B: read Rs -> cand; h' update; write Hs[own], Y; barrier
// Weights from global (L2-resident packed taps), 16-lane-broadcast float4.
// --------------------------------------------------------------------------
template <int HC>
__global__ __launch_bounds__(HC * 16) void gru_rec_kernel(
    const float* __restrict__ A,          // [b][TC][3*HC][64]
    const float* __restrict__ Wgh,        // packed [2*HC][HC][3]
    const float* __restrict__ Wch,        // packed [HC][HC][3]
    const float* hinit,                   // [b][HC][64]
    float* __restrict__ Y, size_t yB,
    float* hfinal) {
  constexpr int OG = 2 * HC;
  constexpr int OCT = 3 * HC;
  const int b = blockIdx.x;
  const int tid = threadIdx.x;
  const int ocg = tid >> 4;          // 0..HC-1
  const int sub = tid & 15;
  const int f0 = sub << 2;           // 0..60
  const bool lo = (sub == 0), hi = (sub == 15);
  __shared__ float Hs[HC][64];
  __shared__ float Rs[HC][64];

  float hreg[4];
  {
    const float4 v = *(const float4*)(hinit + ((size_t)b * HC + ocg) * 64 + f0);
    hreg[0] = v.x; hreg[1] = v.y; hreg[2] = v.z; hreg[3] = v.w;
    *(float4*)&Hs[ocg][f0] = v;
  }
  __syncthreads();

  for (int tl = 0; tl < TC; ++tl) {
    const float* Abt = A + ((size_t)b * TC + tl) * (OCT * 64);
    float accr[4], accu[4], accc[4];
    {
      const float4 vr = *(const float4*)(Abt + (size_t)ocg * 64 + f0);
      const float4 vu = *(const float4*)(Abt + (size_t)(HC + ocg) * 64 + f0);
      const float4 vc = *(const float4*)(Abt + (size_t)(OG + ocg) * 64 + f0);
      accr[0] = vr.x; accr[1] = vr.y; accr[2] = vr.z; accr[3] = vr.w;
      accu[0] = vu.x; accu[1] = vu.y; accu[2] = vu.z; accu[3] = vu.w;
      accc[0] = vc.x; accc[1] = vc.y; accc[2] = vc.z; accc[3] = vc.w;
    }
    // -------- phase A: gates (read Hs) --------
#pragma unroll 2
    for (int hc0 = 0; hc0 < HC; hc0 += 4) {
      float hv[4][6];
#pragma unroll
      for (int q = 0; q < 4; ++q) {
        const float4 h4 = *(const float4*)&Hs[hc0 + q][f0];
        const float lf = __shfl_up(h4.w, 1);
        const float rt = __shfl_down(h4.x, 1);
        hv[q][0] = lo ? 0.f : lf;
        hv[q][1] = h4.x; hv[q][2] = h4.y; hv[q][3] = h4.z; hv[q][4] = h4.w;
        hv[q][5] = hi ? 0.f : rt;
      }
      {
        const float4* w4 = (const float4*)(Wgh + ((size_t)ocg * HC + hc0) * 3);
        const float4 wa = w4[0], wb = w4[1], wc4 = w4[2];
        const float wt[12] = {wa.x, wa.y, wa.z, wa.w, wb.x, wb.y, wb.z, wb.w,
                              wc4.x, wc4.y, wc4.z, wc4.w};
#pragma unroll
        for (int q = 0; q < 4; ++q) {
          const float w0 = wt[3 * q], w1 = wt[3 * q + 1], w2 = wt[3 * q + 2];
#pragma unroll
          for (int ff = 0; ff < 4; ++ff)
            accr[ff] = fmaf(w0, hv[q][ff], fmaf(w1, hv[q][ff + 1], fmaf(w2, hv[q][ff + 2], accr[ff])));
        }
      }
      {
        const float4* w4 = (const float4*)(Wgh + ((size_t)(HC + ocg) * HC + hc0) * 3);
        const float4 wa = w4[0], wb = w4[1], wc4 = w4[2];
        const float wt[12] = {wa.x, wa.y, wa.z, wa.w, wb.x, wb.y, wb.z, wb.w,
                              wc4.x, wc4.y, wc4.z, wc4.w};
#pragma unroll
        for (int q = 0; q < 4; ++q) {
          const float w0 = wt[3 * q], w1 = wt[3 * q + 1], w2 = wt[3 * q + 2];
#pragma unroll
          for (int ff = 0; ff < 4; ++ff)
            accu[ff] = fmaf(w0, hv[q][ff], fmaf(w1, hv[q][ff + 1], fmaf(w2, hv[q][ff + 2], accu[ff])));
        }
      }
    }
    float uu[4];
    {
      float4 rh;
#pragma unroll
      for (int ff = 0; ff < 4; ++ff) {
        uu[ff] = sigmoidf_(accu[ff]);
        (&rh.x)[ff] = sigmoidf_(accr[ff]) * hreg[ff];
      }
      *(float4*)&Rs[ocg][f0] = rh;
    }
    __syncthreads();
    // -------- phase B: cand (read Rs) + state update --------
#pragma unroll 2
    for (int hc0 = 0; hc0 < HC; hc0 += 4) {
      float hv[4][6];
#pragma unroll
      for (int q = 0; q < 4; ++q) {
        const float4 h4 = *(const float4*)&Rs[hc0 + q][f0];
        const float lf = __shfl_up(h4.w, 1);
        const float rt = __shfl_down(h4.x, 1);
        hv[q][0] = lo ? 0.f : lf;
        hv[q][1] = h4.x; hv[q][2] = h4.y; hv[q][3] = h4.z; hv[q][4] = h4.w;
        hv[q][5] = hi ? 0.f : rt;
      }
      const float4* w4 = (const float4*)(Wch + ((size_t)ocg * HC + hc0) * 3);
      const float4 wa = w4[0], wb = w4[1], wc4 = w4[2];
      const float wt[12] = {wa.x, wa.y, wa.z, wa.w, wb.x, wb.y, wb.z, wb.w,
                            wc4.x, wc4.y, wc4.z, wc4.w};
#pragma unroll
      for (int q = 0; q < 4; ++q) {
        const float w0 = wt[3 * q], w1 = wt[3 * q + 1], w2 = wt[3 * q + 2];
#pragma unroll
        for (int ff = 0; ff < 4; ++ff)
          accc[ff] = fmaf(w0, hv[q][ff], fmaf(w1, hv[q][ff + 1], fmaf(w2, hv[q][ff + 2], accc[ff])));
      }
    }
    float4 yv;
#pragma unroll
    for (int ff = 0; ff < 4; ++ff) {
      const float cd = tanhf_(accc[ff]);
      const float hn = fmaf(uu[ff], cd - hreg[ff], hreg[ff]);
      hreg[ff] = hn;
      (&yv.x)[ff] = hn;
    }
    *(float4*)(Y + (size_t)b * yB + (size_t)tl * (HC * 64) + (size_t)ocg * 64 + f0) = yv;
    *(float4*)&Hs[ocg][f0] = yv;
    __syncthreads();
  }
  *(float4*)(hfinal + ((size_t)b * HC + ocg) * 64 + f0) =
      make_float4(hreg[0], hreg[1], hreg[2], hreg[3]);
}

// --------------------------------------------------------------------------
// Small fp32 GEMM: O[b][e] = sum_k W[e][k]*X[b][k] + bias[e], M=64.
// --------------------------------------------------------------------------
template <bool WT>
__global__ __launch_bounds__(256) void gemm64_kernel(
    const float* __restrict__ W, int wrs,
    const float* __restrict__ X, int xrs,
    float* __restrict__ O, int ors,
    const float* __restrict__ bias, int K,
    int ebh, size_t hsW, size_t hsX, size_t hsO, size_t hsB) {
  int eb = blockIdx.x;
  if (ebh > 0) {
    int h = blockIdx.x / ebh;
    eb = blockIdx.x - h * ebh;
    W += h * hsW; X += h * hsX; O += h * hsO;
    if (bias) bias += h * hsB;
  }
  const int e0 = eb * 64;
  __shared__ float Xs[64][68];
  __shared__ float Ws[64][68];
  const int tb4 = (threadIdx.x & 15) << 2;
  const int te4 = (threadIdx.x >> 4) << 2;
  float acc[4][4] = {};
  for (int k0 = 0; k0 < K; k0 += 64) {
    {
      const int row = threadIdx.x >> 2;
      const int kq = (threadIdx.x & 3) << 4;
      const float* src = X + (size_t)row * xrs + k0 + kq;
#pragma unroll
      for (int q = 0; q < 4; ++q) {
        float4 v = *(const float4*)(src + (q << 2));
        Xs[kq + (q << 2) + 0][row] = v.x;
        Xs[kq + (q << 2) + 1][row] = v.y;
        Xs[kq + (q << 2) + 2][row] = v.z;
        Xs[kq + (q << 2) + 3][row] = v.w;
      }
    }
    if (!WT) {
      const int row = threadIdx.x >> 2;
      const int kq = (threadIdx.x & 3) << 4;
      const float* src = W + (size_t)(e0 + row) * wrs + k0 + kq;
#pragma unroll
      for (int q = 0; q < 4; ++q) {
        float4 v = *(const float4*)(src + (q << 2));
        Ws[kq + (q << 2) + 0][row] = v.x;
        Ws[kq + (q << 2) + 1][row] = v.y;
        Ws[kq + (q << 2) + 2][row] = v.z;
        Ws[kq + (q << 2) + 3][row] = v.w;
      }
    } else {
      const int row = threadIdx.x >> 2;
      const int eq = (threadIdx.x & 3) << 4;
      const float* src = W + (size_t)(k0 + row) * wrs + e0 + eq;
#pragma unroll
      for (int q = 0; q < 4; ++q)
        *(float4*)&Ws[row][eq + (q << 2)] = *(const float4*)(src + (q << 2));
    }
    __syncthreads();
#pragma unroll 8
    for (int k = 0; k < 64; ++k) {
      float4 xv = *(const float4*)&Xs[k][tb4];
      float4 wv4 = *(const float4*)&Ws[k][te4];
      const float xb[4] = {xv.x, xv.y, xv.z, xv.w};
      const float we[4] = {wv4.x, wv4.y, wv4.z, wv4.w};
#pragma unroll
      for (int i = 0; i < 4; ++i)
#pragma unroll
        for (int j = 0; j < 4; ++j) acc[i][j] = fmaf(xb[i], we[j], acc[i][j]);
    }
    __syncthreads();
  }
#pragma unroll
  for (int i = 0; i < 4; ++i)
#pragma unroll
    for (int j = 0; j < 4; ++j) {
      float v = acc[i][j];
      if (bias) v += bias[e0 + te4 + j];
      O[(size_t)(tb4 + i) * ors + e0 + te4 + j] = v;
    }
}

// --------------------------------------------------------------------------
// Attention, parallel form (qlen==1, folded).
// --------------------------------------------------------------------------
__global__ __launch_bounds__(256) void attn_scores_kernel(
    const float* __restrict__ qkh, const float* __restrict__ mem,
    float* __restrict__ scores) {
  const int b = blockIdx.x >> 4;
  const int tt = blockIdx.x & 15;
  const int h = threadIdx.x >> 6;
  const int lane = threadIdx.x & 63;
  const float4* qk4 = (const float4*)(qkh + ((size_t)b * 4 + h) * 4096);
#pragma unroll 2
  for (int ti = 0; ti < 8; ++ti) {
    const int t = tt * 8 + ti;
    const float4* m4 = (const float4*)(mem + ((size_t)b * 128 + t) * 4096);
    float s = 0.f;
    for (int e = lane; e < 1024; e += 64) {
      float4 q = qk4[e], m = m4[e];
      s = fmaf(q.x, m.x, fmaf(q.y, m.y, fmaf(q.z, m.z, fmaf(q.w, m.w, s))));
    }
    s = wsum(s);
    if (lane == 0) scores[((size_t)b * 4 + h) * 128 + t] = s;
  }
}

__global__ __launch_bounds__(256) void attn_softmax_kernel(
    const float* __restrict__ scores, const float* __restrict__ qbuf,
    const float* __restrict__ bqkv, float* __restrict__ attnp) {
  const int b = blockIdx.x;
  const int h = threadIdx.x >> 6;
  const int lane = threadIdx.x & 63;
  const float4* q4 = (const float4*)(qbuf + (size_t)b * 4096 + h * 1024);
  const float4* k4 = (const float4*)(bqkv + 4096 + h * 1024);
  float qb = 0.f;
#pragma unroll
  for (int d = lane; d < 256; d += 64) {
    float4 q = q4[d], k = k4[d];
    qb = fmaf(q.x, k.x, fmaf(q.y, k.y, fmaf(q.z, k.z, fmaf(q.w, k.w, qb))));
  }
  qb = wsum(qb);
  const float* sc = scores + ((size_t)b * 4 + h) * 128;
  float s0 = (sc[lane] + qb) * 0.03125f;
  float s1 = (sc[lane + 64] + qb) * 0.03125f;
  float mx = wmaxr(fmaxf(s0, s1));
  float e0v = __expf(s0 - mx), e1v = __expf(s1 - mx);
  float inv = 1.f / wsum(e0v + e1v);
  attnp[((size_t)b * 4 + h) * 128 + lane] = e0v * inv;
  attnp[((size_t)b * 4 + h) * 128 + lane + 64] = e1v * inv;
}

__global__ __launch_bounds__(256) void attn_wsum_kernel(
    const float* __restrict__ attnp, const float* __restrict__ mem,
    float* __restrict__ wmem) {
  const int b = blockIdx.x >> 4;
  const int eb = blockIdx.x & 15;
  const int e = eb * 256 + threadIdx.x;
  __shared__ float ap[4][128];
  for (int i = threadIdx.x; i < 512; i += 256)
    ap[i >> 7][i & 127] = attnp[(size_t)b * 512 + i];
  __syncthreads();
  float a0 = 0, a1 = 0, a2 = 0, a3 = 0;
  const float* mb = mem + (size_t)b * 128 * 4096 + e;
#pragma unroll 4
  for (int t = 0; t < 128; ++t) {
    float m = mb[(size_t)t * 4096];
    a0 = fmaf(ap[0][t], m, a0);
    a1 = fmaf(ap[1][t], m, a1);
    a2 = fmaf(ap[2][t], m, a2);
    a3 = fmaf(ap[3][t], m, a3);
  }
  wmem[((size_t)b * 4 + 0) * 4096 + e] = a0;
  wmem[((size_t)b * 4 + 1) * 4096 + e] = a1;
  wmem[((size_t)b * 4 + 2) * 4096 + e] = a2;
  wmem[((size_t)b * 4 + 3) * 4096 + e] = a3;
}

// --------------------------------------------------------------------------
// Final 1x1 conv for one t-chunk.
// --------------------------------------------------------------------------
__global__ __launch_bounds__(256) void final_kernel(
    const float* __restrict__ z1c,
    const float* __restrict__ wfin, const float* __restrict__ bfin,
    float* __restrict__ out, int tOff) {
  const int idx = blockIdx.x * 256 + threadIdx.x;
  const int f = idx & 63;
  const int tl = (idx >> 6) & 31;
  const int b = idx >> 11;
  const float* zp = z1c + ((size_t)b * TC + tl) * 2048 + f;
  float a = bfin[0];
#pragma unroll
  for (int c = 0; c < 32; ++c) a = fmaf(wfin[c], zp[c * 64], a);
  out[(size_t)b * 8192 + (size_t)(tOff + tl) * 64 + f] = a;
}

// ==========================================================================
extern "C" void kernel_launch(void* const* d_in, const int* in_sizes, int n_in,
                              void* d_out, int out_size, void* d_ws, size_t ws_size,
                              hipStream_t stream) {
  (void)in_sizes; (void)n_in; (void)out_size;
  const float* x     = (const float*)d_in[0];
  const float* wg_e0 = (const float*)d_in[1];
  const float* bg_e0 = (const float*)d_in[2];
  const float* wc_e0 = (const float*)d_in[3];
  const float* bc_e0 = (const float*)d_in[4];
  const float* wg_e1 = (const float*)d_in[5];
  const float* bg_e1 = (const float*)d_in[6];
  const float* wc_e1 = (const float*)d_in[7];
  const float* bc_e1 = (const float*)d_in[8];
  const float* wg_d0 = (const float*)d_in[9];
  const float* bg_d0 = (const float*)d_in[10];
  const float* wc_d0 = (const float*)d_in[11];
  const float* bc_d0 = (const float*)d_in[12];
  const float* wg_d1 = (const float*)d_in[13];
  const float* bg_d1 = (const float*)d_in[14];
  const float* wc_d1 = (const float*)d_in[15];
  const float* bc_d1 = (const float*)d_in[16];
  const float* w_qkv = (const float*)d_in[17];
  const float* b_qkv = (const float*)d_in[18];
  const float* w_out = (const float*)d_in[19];
  const float* b_out = (const float*)d_in[20];
  const float* w_fin = (const float*)d_in[21];
  const float* b_fin = (const float*)d_in[22];
  float* out = (float*)d_out;

  float* WS = (float*)d_ws;
  size_t off = 0;
  auto alloc = [&](size_t n) { float* p = WS + off; off += (n + 63) & ~(size_t)63; return p; };
  float* A    = alloc((size_t)B_ * TC * 192 * 64);
  float* Y0c  = alloc((size_t)B_ * TC * 32 * 64);
  float* Y1   = alloc((size_t)B_ * T_ * 64 * 64);
  float* Z0c  = alloc((size_t)B_ * TC * 64 * 64);
  float* Z1c  = alloc((size_t)B_ * TC * 32 * 64);
  float* He0p[2] = {alloc((size_t)B_ * 32 * 64), alloc((size_t)B_ * 32 * 64)};
  float* He1p[2] = {alloc((size_t)B_ * 64 * 64), alloc((size_t)B_ * 64 * 64)};
  float* Hd0p[2] = {alloc((size_t)B_ * 64 * 64), alloc((size_t)B_ * 64 * 64)};
  float* Hd1p[2] = {alloc((size_t)B_ * 32 * 64), alloc((size_t)B_ * 32 * 64)};
  float* QBUF = alloc((size_t)B_ * 4096);
  float* QKH  = alloc((size_t)B_ * 4 * 4096);
  float* WMEM = alloc((size_t)B_ * 4 * 4096);
  float* CTXB = alloc((size_t)B_ * 4096);
  float* CTXO = alloc((size_t)B_ * 4096);
  float* SCR  = alloc((size_t)B_ * 4 * 128);
  float* ATTN = alloc((size_t)B_ * 4 * 128);
  float* wgx_e0 = alloc(64 * 1 * 3);    float* wgh_e0 = alloc(64 * 32 * 3);
  float* wcx_e0 = alloc(32 * 1 * 3);    float* wch_e0 = alloc(32 * 32 * 3);
  float* wgx_e1 = alloc(128 * 32 * 3);  float* wgh_e1 = alloc(128 * 64 * 3);
  float* wcx_e1 = alloc(64 * 32 * 3);   float* wch_e1 = alloc(64 * 64 * 3);
  float* wgx_d0 = alloc(128 * 128 * 3); float* wgh_d0 = alloc(128 * 64 * 3);
  float* wcx_d0 = alloc(64 * 128 * 3);  float* wch_d0 = alloc(64 * 64 * 3);
  float* wgx_d1 = alloc(64 * 64 * 3);   float* wgh_d1 = alloc(64 * 32 * 3);
  float* wcx_d1 = alloc(32 * 64 * 3);   float* wch_d1 = alloc(32 * 32 * 3);
  if (ws_size < off * sizeof(float)) return;

  // Fused weight repack (16 jobs, one launch).
  {
    PackArgs pa;
    const float* srcs[16] = {wg_e0, wg_e0, wc_e0, wc_e0, wg_e1, wg_e1, wc_e1, wc_e1,
                             wg_d0, wg_d0, wc_d0, wc_d0, wg_d1, wg_d1, wc_d1, wc_d1};
    float* dsts[16] = {wgx_e0, wgh_e0, wcx_e0, wch_e0, wgx_e1, wgh_e1, wcx_e1, wch_e1,
                       wgx_d0, wgh_d0, wcx_d0, wch_d0, wgx_d1, wgh_d1, wcx_d1, wch_d1};
    int intot[16] = {33, 33, 33, 33, 96, 96, 96, 96, 192, 192, 192, 192, 96, 96, 96, 96};
    int ic0[16]   = {0, 1, 0, 1, 0, 32, 0, 32, 0, 128, 0, 128, 0, 64, 0, 64};
    int icn[16]   = {1, 32, 1, 32, 32, 64, 32, 64, 128, 64, 128, 64, 64, 32, 64, 32};
    int occ[16]   = {64, 64, 32, 32, 128, 128, 64, 64, 128, 128, 64, 64, 64, 64, 32, 32};
    for (int j = 0; j < 16; ++j) {
      pa.src[j] = srcs[j]; pa.dst[j] = dsts[j];
      pa.intot[j] = intot[j]; pa.ic0[j] = ic0[j]; pa.icn[j] = icn[j]; pa.oc[j] = occ[j];
    }
    pack_all_kernel<<<dim3(192, 16), 256, 0, stream>>>(pa);
  }

  hipMemsetAsync(He0p[0], 0, (size_t)B_ * 32 * 64 * 4, stream);
  hipMemsetAsync(He1p[0], 0, (size_t)B_ * 64 * 64 * 4, stream);

  // -------- encoder --------
  for (int c = 0; c < NCH; ++c) {
    conv_x_kernel<1, 64, 32><<<2048, 256, 0, stream>>>(
        x + (size_t)c * TC * 64, 1, (size_t)T_ * 64, nullptr,
        wgx_e0, wcx_e0, bg_e0, bc_e0, A);
    gru_rec_kernel<32><<<64, 512, 0, stream>>>(
        A, wgh_e0, wch_e0, He0p[c & 1], Y0c, (size_t)TC * 32 * 64, He0p[(c + 1) & 1]);
    conv_x_kernel<32, 128, 64><<<2048, 256, 0, stream>>>(
        Y0c, 32, (size_t)TC * 32 * 64, nullptr,
        wgx_e1, wcx_e1, bg_e1, bc_e1, A);
    gru_rec_kernel<64><<<64, 1024, 0, stream>>>(
        A, wgh_e1, wch_e1, He1p[c & 1], Y1 + (size_t)c * TC * 4096, (size_t)T_ * 4096,
        He1p[(c + 1) & 1]);
  }
  float* He0f = He0p[0];
  float* He1f = He1p[0];

  // -------- attention (query len 1, folded) --------
  const float* wq = w_qkv;
  const float* wk = w_qkv + (size_t)4096 * 4096;
  const float* wv = w_qkv + (size_t)8192 * 4096;
  gemm64_kernel<false><<<64, 256, 0, stream>>>(wq, 4096, He1f, 4096, QBUF, 4096,
                                               b_qkv, 4096, 0, 0, 0, 0, 0);
  gemm64_kernel<true><<<256, 256, 0, stream>>>(wk, 4096, QBUF, 4096, QKH, 16384,
                                               nullptr, 1024, 64,
                                               (size_t)1024 * 4096, 1024, 4096, 0);
  attn_scores_kernel<<<B_ * 16, 256, 0, stream>>>(QKH, Y1, SCR);
  attn_softmax_kernel<<<B_, 256, 0, stream>>>(SCR, QBUF, b_qkv, ATTN);
  attn_wsum_kernel<<<B_ * 16, 256, 0, stream>>>(ATTN, Y1, WMEM);
  gemm64_kernel<false><<<64, 256, 0, stream>>>(wv, 4096, WMEM, 16384, CTXB, 4096,
                                               b_qkv + 8192, 4096, 16,
                                               (size_t)1024 * 4096, 4096, 1024, 1024);
  gemm64_kernel<false><<<64, 256, 0, stream>>>(w_out, 4096, CTXB, 4096, CTXO, 4096,
                                               b_out, 4096, 0, 0, 0, 0, 0);

  // -------- decoder --------
  for (int c = 0; c < NCH; ++c) {
    conv_x_kernel<128, 128, 64><<<2048, 256, 0, stream>>>(
        Y1 + (size_t)c * TC * 4096, 64, (size_t)T_ * 4096, CTXO,
        wgx_d0, wcx_d0, bg_d0, bc_d0, A);
    gru_rec_kernel<64><<<64, 1024, 0, stream>>>(
        A, wgh_d0, wch_d0, (c == 0 ? He1f : Hd0p[c & 1]), Z0c, (size_t)TC * 4096,
        Hd0p[(c + 1) & 1]);
    conv_x_kernel<64, 64, 32><<<2048, 256, 0, stream>>>(
        Z0c, 64, (size_t)TC * 4096, nullptr,
        wgx_d1, wcx_d1, bg_d1, bc_d1, A);
    gru_rec_kernel<32><<<64, 512, 0, stream>>>(
        A, wgh_d1, wch_d1, (c == 0 ? He0f : Hd1p[c & 1]), Z1c, (size_t)TC * 2048,
        Hd1p[(c + 1) & 1]);
    final_kernel<<<512, 256, 0, stream>>>(Z1c, w_fin, b_fin, out, c * TC);
  }
}